// Round 18
// baseline (443.812 us; speedup 1.0000x reference)
//
#include <hip/hip_runtime.h>
#include <hip/hip_bf16.h>
#include <math.h>

// Problem constants
constexpr int N = 10000;
constexpr int E = 160000;
constexpr int B = 16;
constexpr int PC = 625;           // pool partial chunks (= prepool grid)
constexpr int MS = 72;            // m_s row stride (bf16)
constexpr int HS = 96;            // hb row stride: 4 q-sections x 24 (17 used + pad)

typedef short bf16x8 __attribute__((ext_vector_type(8)));
typedef short bf16x4 __attribute__((ext_vector_type(4)));
typedef float f32x4 __attribute__((ext_vector_type(4)));

__device__ __forceinline__ float silu_f(float x) {
    return x / (1.0f + __expf(-x));
}
__device__ __forceinline__ float bf2f(short s) {
    union { unsigned u; float f; } c; c.u = (unsigned)(unsigned short)s << 16; return c.f;
}

// ---------------- fused weight reorder ----------------
__device__ __forceinline__ void hilo_store(float wv, __hip_bfloat16* hi, __hip_bfloat16* lo, int idx) {
    __hip_bfloat16 hh = __float2bfloat16(wv);
    hi[idx] = hh;
    lo[idx] = __float2bfloat16(wv - __bfloat162float(hh));
}
__device__ __forceinline__ float zr64q(const float* __restrict__ W, int idx) {
    int l = idx >> 15;
    int rem = idx & 32767;
    int kk = rem >> 11, nt = (rem >> 9) & 3, c = (rem >> 5) & 15, q = (rem >> 3) & 3, j = rem & 7;
    return W[(size_t)l * 32768 + (size_t)(q * 16 + kk) * 512 + j * 64 + nt * 16 + c];
}
__device__ __forceinline__ float wu1q(const float* __restrict__ W, int idx) {
    int l = idx / 67584;
    int rem = idx % 67584;
    int kk = rem / 2048;
    int r2 = rem % 2048;
    int nt = (r2 >> 9) & 3, c = (r2 >> 5) & 15, q = (r2 >> 3) & 3, j = r2 & 7;
    int i = q * 33 + kk;
    return (i < 129) ? W[(size_t)l * 129 * 512 + (size_t)i * 512 + j * 64 + nt * 16 + c] : 0.f;
}
__device__ __forceinline__ float wm1zq(const float* __restrict__ W, int idx) {
    int l = idx / 71680;
    int rem = idx % 71680;
    int kkn = rem >> 9;
    int off = rem & 511;
    int kk = kkn >> 2;
    int nt = kkn & 3;
    int c16 = off >> 5;
    int q = (off >> 3) & 3;
    int j = off & 7;
    int k = nt * 16 + c16;
    int wi = -1;
    if (kk < 17) { int i = q * 17 + kk; if (i <= 64) wi = i; }
    else if (kk < 34) { int s = q * 17 + (kk - 17); if (s <= 64) wi = 65 + s; }
    else { if (q == 0) wi = 130; }
    return (wi >= 0) ? W[((size_t)l * 131 + wi) * 512 + j * 64 + k] : 0.f;
}
__global__ __launch_bounds__(256) void k_reorder(
        const float* __restrict__ Wm2, const float* __restrict__ Wm1,
        const float* __restrict__ Wu1, const float* __restrict__ Wu2,
        const float* __restrict__ Wp1, const float* __restrict__ Wp2,
        __hip_bfloat16* W2hi, __hip_bfloat16* Wm1zhi,
        __hip_bfloat16* Wu1hi, __hip_bfloat16* Wu1lo,
        __hip_bfloat16* Wu2hi, __hip_bfloat16* Wu2lo,
        __hip_bfloat16* Wp1hi, __hip_bfloat16* Wp1lo,
        __hip_bfloat16* Wp2hi, __hip_bfloat16* Wp2lo) {
    int idx = blockIdx.x * 256 + threadIdx.x;
    if (idx < 65536)        W2hi[idx] = __float2bfloat16(zr64q(Wm2, idx));
    else if (idx < 208896) { int i2 = idx - 65536;  Wm1zhi[i2] = __float2bfloat16(wm1zq(Wm1, i2)); }
    else if (idx < 344064) { int i2 = idx - 208896; hilo_store(wu1q(Wu1, i2), Wu1hi, Wu1lo, i2); }
    else if (idx < 409600) { int i2 = idx - 344064; hilo_store(zr64q(Wu2, i2), Wu2hi, Wu2lo, i2); }
    else if (idx < 442368) { int i2 = idx - 409600; hilo_store(zr64q(Wp1, i2), Wp1hi, Wp1lo, i2); }
    else if (idx < 475136) { int i2 = idx - 442368; hilo_store(zr64q(Wp2, i2), Wp2hi, Wp2lo, i2); }
}

// ---------------- device helper: one z-GEMM stage (hi/lo), 4 waves split K, q-major x ----------------
__device__ __forceinline__ void zgemm_stage(
        const __hip_bfloat16* xsrc, int xstride, int kkmax, int Lq,
        int w, int c16, int q, int lofs, const float* naA,
        const __hip_bfloat16* __restrict__ Whi, const __hip_bfloat16* __restrict__ Wlo,
        float (*part_s)[16][64]) {
    f32x4 zero4 = {0.f, 0.f, 0.f, 0.f};
    f32x4 acc[4];
#pragma unroll
    for (int nt = 0; nt < 4; ++nt) acc[nt] = zero4;
    for (int kk = w; kk < kkmax; kk += 4) {
        bf16x8 bh[4], bl[4];
#pragma unroll
        for (int nt = 0; nt < 4; ++nt) {
            int off = (kk * 4 + nt) * 512 + lofs;
            bh[nt] = *(const bf16x8*)(Whi + off);
            bl[nt] = *(const bf16x8*)(Wlo + off);
        }
        float mv = __bfloat162float(xsrc[c16 * xstride + q * Lq + kk]);
        union { bf16x8 v; __hip_bfloat16 hx[8]; } au;
#pragma unroll
        for (int j = 0; j < 8; ++j) au.hx[j] = __float2bfloat16(mv * naA[j]);
#pragma unroll
        for (int nt = 0; nt < 4; ++nt) {
            acc[nt] = __builtin_amdgcn_mfma_f32_16x16x32_bf16(au.v, bh[nt], acc[nt], 0, 0, 0);
            acc[nt] = __builtin_amdgcn_mfma_f32_16x16x32_bf16(au.v, bl[nt], acc[nt], 0, 0, 0);
        }
    }
#pragma unroll
    for (int nt = 0; nt < 4; ++nt)
#pragma unroll
        for (int r = 0; r < 4; ++r) part_s[w][q * 4 + r][nt * 16 + c16] = acc[nt][r];
}

// ---------------- K1: embed -> h fp32 + hb (q-sectioned) + agg zero ----------------
__global__ __launch_bounds__(256) void k_embed_hb(
        const float* __restrict__ x, const float* __restrict__ anf,
        const float* __restrict__ na, const float* __restrict__ W_emb,
        const float* __restrict__ b_emb,
        float* __restrict__ h, __hip_bfloat16* __restrict__ hb, float* __restrict__ agg) {
    __shared__ float xs[16][18];
    __shared__ float na_s[16][8];
    int tid = threadIdx.x, w = tid >> 6, l = tid & 63;
    int n0 = blockIdx.x * 16;
    {
        int r = tid >> 4, c = tid & 15;
        xs[r][c] = x[(size_t)(n0 + r) * 16 + c];
    }
    if (tid < 16) xs[tid][16] = anf[n0 + tid];
    if (tid < 128) na_s[tid >> 3][tid & 7] = na[(size_t)n0 * 8 + tid];
    float4 z4 = {0.f, 0.f, 0.f, 0.f};
    ((float4*)(agg + (size_t)blockIdx.x * 1024))[tid] = z4;
    for (int t = tid; t < 192; t += 256)
        ((float4*)(hb + (size_t)n0 * HS))[t] = z4;
    __syncthreads();
    float acc[4];
#pragma unroll
    for (int t = 0; t < 4; ++t) acc[t] = b_emb[l];
    for (int i = 0; i < 17; ++i) {
#pragma unroll
        for (int j = 0; j < 8; ++j) {
            float wv = W_emb[(i * 8 + j) * 64 + l];
#pragma unroll
            for (int t = 0; t < 4; ++t) {
                int nn = w * 4 + t;
                acc[t] = fmaf(xs[nn][i] * na_s[nn][j], wv, acc[t]);
            }
        }
    }
    int slot = (l / 17) * 24 + l % 17;
#pragma unroll
    for (int t = 0; t < 4; ++t) {
        int n = n0 + w * 4 + t;
        h[(size_t)n * 64 + l] = acc[t];
        hb[(size_t)n * HS + slot] = __float2bfloat16(acc[t]);
    }
    if (tid < 16) hb[(size_t)(n0 + tid) * HS + 85] = __float2bfloat16(xs[tid][16]);  // i=64 -> 3*24+13
}

// ---------------- K3: edge kernel (R16-exact) ----------------
__global__ __launch_bounds__(256, 4) void k_edge(
        const int* __restrict__ eidx, const float* __restrict__ ea,
        const float* __restrict__ amf, const __hip_bfloat16* __restrict__ hb,
        const __hip_bfloat16* __restrict__ W1hi, const float* __restrict__ bm1_l,
        const __hip_bfloat16* __restrict__ W2hi,
        const float* __restrict__ bm2_l, float* __restrict__ agg) {
    __shared__ __align__(16) __hip_bfloat16 m_s[128 * MS];
    __shared__ float ea_s[128][9];
    __shared__ float amf_s[128];
    __shared__ int src_s[128], dst_s[128];
    __shared__ float bm1_s[64], bm2_s[64];
    int tid = threadIdx.x;
    int l = tid & 63, w = tid >> 6;
    int e0 = blockIdx.x * 128;
    for (int idx = tid; idx < 128; idx += 256) {
        src_s[idx] = eidx[e0 + idx];
        dst_s[idx] = eidx[E + e0 + idx];
        amf_s[idx] = amf[e0 + idx];
    }
    for (int idx = tid; idx < 1024; idx += 256) ea_s[idx >> 3][idx & 7] = ea[(size_t)e0 * 8 + idx];
    if (tid < 64) { bm1_s[tid] = bm1_l[tid]; bm2_s[tid] = bm2_l[tid]; }
    __syncthreads();

    int c16 = l & 15, q = l >> 4;
    int e0w = w * 32;
    float eaA[2][8];
    float amfA[2];
#pragma unroll
    for (int mt = 0; mt < 2; ++mt) {
#pragma unroll
        for (int j = 0; j < 8; ++j) eaA[mt][j] = ea_s[e0w + mt * 16 + c16][j];
        amfA[mt] = amf_s[e0w + mt * 16 + c16];
    }
    int lofs = (c16 * 4 + q) * 8;
    f32x4 zero4 = {0.f, 0.f, 0.f, 0.f};

    bf16x4 xD[2][5], xS[2][5];
#pragma unroll
    for (int mt = 0; mt < 2; ++mt) {
        const __hip_bfloat16* bd = hb + (size_t)dst_s[e0w + mt * 16 + c16] * HS + q * 24;
        const __hip_bfloat16* bs = hb + (size_t)src_s[e0w + mt * 16 + c16] * HS + q * 24;
#pragma unroll
        for (int t = 0; t < 5; ++t) {
            xD[mt][t] = *(const bf16x4*)(bd + t * 4);
            xS[mt][t] = *(const bf16x4*)(bs + t * 4);
        }
    }

    // phase 1
    f32x4 acc1[2][4];
#pragma unroll
    for (int mt = 0; mt < 2; ++mt)
#pragma unroll
        for (int nt = 0; nt < 4; ++nt) acc1[mt][nt] = zero4;
#pragma unroll
    for (int kk = 0; kk < 17; ++kk) {
        bf16x8 bh[4];
#pragma unroll
        for (int nt = 0; nt < 4; ++nt)
            bh[nt] = *(const bf16x8*)(W1hi + (kk * 4 + nt) * 512 + lofs);
#pragma unroll
        for (int mt = 0; mt < 2; ++mt) {
            float xv = bf2f(xD[mt][kk >> 2][kk & 3]);
            union { bf16x8 v; __hip_bfloat16 hx[8]; } au;
#pragma unroll
            for (int j = 0; j < 8; ++j) au.hx[j] = __float2bfloat16(xv * eaA[mt][j]);
#pragma unroll
            for (int nt = 0; nt < 4; ++nt)
                acc1[mt][nt] = __builtin_amdgcn_mfma_f32_16x16x32_bf16(au.v, bh[nt], acc1[mt][nt], 0, 0, 0);
        }
    }
#pragma unroll
    for (int kk = 0; kk < 17; ++kk) {
        bf16x8 bh[4];
#pragma unroll
        for (int nt = 0; nt < 4; ++nt)
            bh[nt] = *(const bf16x8*)(W1hi + ((17 + kk) * 4 + nt) * 512 + lofs);
#pragma unroll
        for (int mt = 0; mt < 2; ++mt) {
            float xv = bf2f(xS[mt][kk >> 2][kk & 3]);
            union { bf16x8 v; __hip_bfloat16 hx[8]; } au;
#pragma unroll
            for (int j = 0; j < 8; ++j) au.hx[j] = __float2bfloat16(xv * eaA[mt][j]);
#pragma unroll
            for (int nt = 0; nt < 4; ++nt)
                acc1[mt][nt] = __builtin_amdgcn_mfma_f32_16x16x32_bf16(au.v, bh[nt], acc1[mt][nt], 0, 0, 0);
        }
    }
    {   // amf chunk (kk=34): only q==0 rows carry amf
        bf16x8 bh[4];
#pragma unroll
        for (int nt = 0; nt < 4; ++nt)
            bh[nt] = *(const bf16x8*)(W1hi + (34 * 4 + nt) * 512 + lofs);
#pragma unroll
        for (int mt = 0; mt < 2; ++mt) {
            float xv = (q == 0) ? amfA[mt] : 0.f;
            union { bf16x8 v; __hip_bfloat16 hx[8]; } au;
#pragma unroll
            for (int j = 0; j < 8; ++j) au.hx[j] = __float2bfloat16(xv * eaA[mt][j]);
#pragma unroll
            for (int nt = 0; nt < 4; ++nt)
                acc1[mt][nt] = __builtin_amdgcn_mfma_f32_16x16x32_bf16(au.v, bh[nt], acc1[mt][nt], 0, 0, 0);
        }
    }
#pragma unroll
    for (int mt = 0; mt < 2; ++mt)
#pragma unroll
        for (int nt = 0; nt < 4; ++nt) {
            int kd = nt * 16 + c16;
            float bias = bm1_s[kd];
#pragma unroll
            for (int r = 0; r < 4; ++r) {
                int e = e0w + mt * 16 + q * 4 + r;
                m_s[e * MS + kd] = __float2bfloat16(silu_f(bias + acc1[mt][nt][r]));
            }
        }

    // phase 2 (hi-only)
    bf16x4 mR[2][4];
#pragma unroll
    for (int mt = 0; mt < 2; ++mt)
#pragma unroll
        for (int t = 0; t < 4; ++t)
            mR[mt][t] = *(const bf16x4*)&m_s[(e0w + mt * 16 + c16) * MS + q * 16 + t * 4];

    f32x4 acc[2][4];
#pragma unroll
    for (int mt = 0; mt < 2; ++mt)
#pragma unroll
        for (int nt = 0; nt < 4; ++nt) acc[mt][nt] = zero4;
#pragma unroll
    for (int kk = 0; kk < 16; ++kk) {
        bf16x8 bh[4];
#pragma unroll
        for (int nt = 0; nt < 4; ++nt)
            bh[nt] = *(const bf16x8*)(W2hi + (kk * 4 + nt) * 512 + lofs);
#pragma unroll
        for (int mt = 0; mt < 2; ++mt) {
            float mv = bf2f(mR[mt][kk >> 2][kk & 3]);
            union { bf16x8 v; __hip_bfloat16 h[8]; } au;
#pragma unroll
            for (int j = 0; j < 8; ++j) au.h[j] = __float2bfloat16(mv * eaA[mt][j]);
#pragma unroll
            for (int nt = 0; nt < 4; ++nt)
                acc[mt][nt] = __builtin_amdgcn_mfma_f32_16x16x32_bf16(au.v, bh[nt], acc[mt][nt], 0, 0, 0);
        }
    }
#pragma unroll
    for (int mt = 0; mt < 2; ++mt)
#pragma unroll
        for (int nt = 0; nt < 4; ++nt) {
            int kd = nt * 16 + c16;
            float bias = bm2_s[kd];
#pragma unroll
            for (int r = 0; r < 4; ++r) {
                int e = e0w + mt * 16 + q * 4 + r;
                float v = silu_f(bias + acc[mt][nt][r]);
                atomicAdd(&agg[(size_t)dst_s[e] * 64 + kd], v);
            }
        }
}

// ---------------- K4: node update + write h/hb + agg zero (R16-exact) ----------------
__global__ __launch_bounds__(256) void k_upd_hb(
        const float* __restrict__ h_in, const float* __restrict__ anf,
        const float* __restrict__ na, const float* __restrict__ agg_in,
        const __hip_bfloat16* __restrict__ W1hi, const __hip_bfloat16* __restrict__ W1lo,
        const float* __restrict__ bu1_l,
        const __hip_bfloat16* __restrict__ W2hi_, const __hip_bfloat16* __restrict__ W2lo_,
        const float* __restrict__ bu2_l,
        float* __restrict__ h, __hip_bfloat16* __restrict__ hb, float* __restrict__ agg) {
    __shared__ __align__(16) __hip_bfloat16 xa_s[16 * 136];
    __shared__ __align__(16) __hip_bfloat16 u1_s[16 * 72];
    __shared__ float part_s[4][16][64];
    int tid = threadIdx.x;
    int w = tid >> 6, l = tid & 63;
    int n0 = blockIdx.x * 16;
    for (int idx = tid; idx < 16 * 132; idx += 256) {
        int r = idx / 132, c = idx % 132;
        int n = n0 + r;
        float v;
        if (c < 64) v = h_in[(size_t)n * 64 + c];
        else if (c == 64) v = anf[n];
        else if (c < 129) v = agg_in[(size_t)n * 64 + (c - 65)];
        else v = 0.f;
        xa_s[r * 136 + c] = __float2bfloat16(v);
    }
    int c16 = l & 15, q = l >> 4;
    float naA[8];
#pragma unroll
    for (int j = 0; j < 8; ++j) naA[j] = na[(size_t)(n0 + c16) * 8 + j];
    __syncthreads();
    float4 z4 = {0.f, 0.f, 0.f, 0.f};
    ((float4*)(agg + (size_t)blockIdx.x * 1024))[tid] = z4;
    for (int t = tid; t < 192; t += 256)
        ((float4*)(hb + (size_t)n0 * HS))[t] = z4;
    int lofs = (c16 * 4 + q) * 8;
    zgemm_stage(xa_s, 136, 33, 33, w, c16, q, lofs, naA, W1hi, W1lo, part_s);
    __syncthreads();
    for (int t = tid; t < 1024; t += 256) {
        int row = t >> 6, col = t & 63;
        float v = part_s[0][row][col] + part_s[1][row][col] + part_s[2][row][col] +
                  part_s[3][row][col] + bu1_l[col];
        u1_s[row * 72 + col] = __float2bfloat16(silu_f(v));
    }
    __syncthreads();
    zgemm_stage(u1_s, 72, 16, 16, w, c16, q, lofs, naA, W2hi_, W2lo_, part_s);
    __syncthreads();
    for (int t = tid; t < 1024; t += 256) {
        int row = t >> 6, col = t & 63;
        float v = part_s[0][row][col] + part_s[1][row][col] + part_s[2][row][col] +
                  part_s[3][row][col] + bu2_l[col];
        int n = n0 + row;
        float hn = h[(size_t)n * 64 + col] + v;
        h[(size_t)n * 64 + col] = hn;
        hb[(size_t)n * HS + (col / 17) * 24 + col % 17] = __float2bfloat16(hn);
    }
    if (tid < 16) hb[(size_t)(n0 + tid) * HS + 85] = __float2bfloat16(anf[n0 + tid]);
}

// ---------------- K6: fused node update (layer 1) + prepool + in-block pooling ----------------
__global__ __launch_bounds__(256) void k_upd_prepool(
        const float* __restrict__ h_in, const float* __restrict__ anf,
        const float* __restrict__ na, const float* __restrict__ agg_in,
        const int* __restrict__ batch,
        const __hip_bfloat16* __restrict__ W1hi, const __hip_bfloat16* __restrict__ W1lo,
        const float* __restrict__ bu1_l,
        const __hip_bfloat16* __restrict__ W2hi_, const __hip_bfloat16* __restrict__ W2lo_,
        const float* __restrict__ bu2_l,
        const __hip_bfloat16* __restrict__ Wp1hi, const __hip_bfloat16* __restrict__ Wp1lo,
        const float* __restrict__ bp1,
        const __hip_bfloat16* __restrict__ Wp2hi, const __hip_bfloat16* __restrict__ Wp2lo,
        const float* __restrict__ bp2,
        float* __restrict__ partial_p, float* __restrict__ partial_cnt) {
    __shared__ __align__(16) __hip_bfloat16 xa_s[16 * 136];
    __shared__ __align__(16) __hip_bfloat16 u1_s[16 * 72];
    __shared__ __align__(16) __hip_bfloat16 x2_s[16 * 72];
    __shared__ float part_s[4][16][64];
    __shared__ float pool_s[16][64];
    __shared__ float cnt_s[16];
    __shared__ int batch_s[16];
    int tid = threadIdx.x;
    int w = tid >> 6, l = tid & 63;
    int n0 = blockIdx.x * 16;
    for (int idx = tid; idx < 1024; idx += 256) pool_s[idx >> 6][idx & 63] = 0.f;
    if (tid < 16) { cnt_s[tid] = 0.f; batch_s[tid] = batch[n0 + tid]; }
    for (int idx = tid; idx < 16 * 132; idx += 256) {
        int r = idx / 132, c = idx % 132;
        int n = n0 + r;
        float v;
        if (c < 64) v = h_in[(size_t)n * 64 + c];
        else if (c == 64) v = anf[n];
        else if (c < 129) v = agg_in[(size_t)n * 64 + (c - 65)];
        else v = 0.f;
        xa_s[r * 136 + c] = __float2bfloat16(v);
    }
    int c16 = l & 15, q = l >> 4;
    float naA[8];
#pragma unroll
    for (int j = 0; j < 8; ++j) naA[j] = na[(size_t)(n0 + c16) * 8 + j];
    __syncthreads();
    if (tid < 16) atomicAdd(&cnt_s[batch_s[tid]], 1.0f);
    int lofs = (c16 * 4 + q) * 8;
    zgemm_stage(xa_s, 136, 33, 33, w, c16, q, lofs, naA, W1hi, W1lo, part_s);
    __syncthreads();
    for (int t = tid; t < 1024; t += 256) {
        int row = t >> 6, col = t & 63;
        float v = part_s[0][row][col] + part_s[1][row][col] + part_s[2][row][col] +
                  part_s[3][row][col] + bu1_l[col];
        u1_s[row * 72 + col] = __float2bfloat16(silu_f(v));
    }
    __syncthreads();
    zgemm_stage(u1_s, 72, 16, 16, w, c16, q, lofs, naA, W2hi_, W2lo_, part_s);
    __syncthreads();
    for (int t = tid; t < 1024; t += 256) {
        int row = t >> 6, col = t & 63;
        float v = part_s[0][row][col] + part_s[1][row][col] + part_s[2][row][col] +
                  part_s[3][row][col] + bu2_l[col];
        float hn = h_in[(size_t)(n0 + row) * 64 + col] + v;
        x2_s[row * 72 + col] = __float2bfloat16(hn);
    }
    __syncthreads();
    zgemm_stage(x2_s, 72, 16, 16, w, c16, q, lofs, naA, Wp1hi, Wp1lo, part_s);
    __syncthreads();
    for (int t = tid; t < 1024; t += 256) {
        int row = t >> 6, col = t & 63;
        float v = part_s[0][row][col] + part_s[1][row][col] + part_s[2][row][col] +
                  part_s[3][row][col] + bp1[col];
        u1_s[row * 72 + col] = __float2bfloat16(silu_f(v));
    }
    __syncthreads();
    zgemm_stage(u1_s, 72, 16, 16, w, c16, q, lofs, naA, Wp2hi, Wp2lo, part_s);
    __syncthreads();
    for (int t = tid; t < 1024; t += 256) {
        int row = t >> 6, col = t & 63;
        float v = part_s[0][row][col] + part_s[1][row][col] + part_s[2][row][col] +
                  part_s[3][row][col] + bp2[col];
        atomicAdd(&pool_s[batch_s[row]][col], v);
    }
    __syncthreads();
    for (int t = tid; t < 1024; t += 256)
        partial_p[(size_t)blockIdx.x * 1024 + t] = pool_s[t >> 6][t & 63];
    if (tid < 16) partial_cnt[blockIdx.x * 16 + tid] = cnt_s[tid];
}

// ---------------- K7: reduce 625 partials, mean, final MLP (one block per graph) ----------------
__global__ __launch_bounds__(256) void k_final(
        const float* __restrict__ partial_p, const float* __restrict__ partial_cnt,
        const float* __restrict__ Wq1, const float* __restrict__ bq1,
        const float* __restrict__ Wq2, const float* __restrict__ bq2,
        float* __restrict__ out) {
    __shared__ float red[4][64];
    __shared__ float cred[4];
    __shared__ float g_s[64];
    int b = blockIdx.x;
    int tid = threadIdx.x;
    int k = tid & 63, part = tid >> 6;
    float s = 0.f;
    for (int c = part; c < PC; c += 4) s += partial_p[(size_t)c * 1024 + b * 64 + k];
    red[part][k] = s;
    if (k == 0) {
        float cc = 0.f;
        for (int c = part; c < PC; c += 4) cc += partial_cnt[c * 16 + b];
        cred[part] = cc;
    }
    __syncthreads();
    if (tid < 64) {
        float cnt = cred[0] + cred[1] + cred[2] + cred[3];
        g_s[k] = (red[0][k] + red[1][k] + red[2][k] + red[3][k]) / fmaxf(cnt, 1.0f);
    }
    __syncthreads();
    if (tid < 64) {
        float acc = bq1[k];
#pragma unroll
        for (int i = 0; i < 64; ++i) acc = fmaf(g_s[i], Wq1[i * 64 + k], acc);
        float v = silu_f(acc) * Wq2[k];
#pragma unroll
        for (int off = 32; off > 0; off >>= 1) v += __shfl_down(v, off, 64);
        if (k == 0) out[b] = v + bq2[0];
    }
}

extern "C" void kernel_launch(void* const* d_in, const int* in_sizes, int n_in,
                              void* d_out, int out_size, void* d_ws, size_t ws_size,
                              hipStream_t stream) {
    const float* x    = (const float*)d_in[0];
    const int*   eidx = (const int*)  d_in[1];
    const float* ea   = (const float*)d_in[2];
    const float* na   = (const float*)d_in[3];
    const float* amf  = (const float*)d_in[4];
    const float* anf  = (const float*)d_in[5];
    const int*   batch= (const int*)  d_in[6];
    const float* W_emb= (const float*)d_in[7];
    const float* b_emb= (const float*)d_in[8];
    const float* Wm1  = (const float*)d_in[9];
    const float* bm1  = (const float*)d_in[10];
    const float* Wm2  = (const float*)d_in[11];
    const float* bm2  = (const float*)d_in[12];
    const float* Wu1  = (const float*)d_in[13];
    const float* bu1  = (const float*)d_in[14];
    const float* Wu2  = (const float*)d_in[15];
    const float* bu2  = (const float*)d_in[16];
    const float* Wp1  = (const float*)d_in[17];
    const float* bp1  = (const float*)d_in[18];
    const float* Wp2  = (const float*)d_in[19];
    const float* bp2  = (const float*)d_in[20];
    const float* Wq1  = (const float*)d_in[21];
    const float* bq1  = (const float*)d_in[22];
    const float* Wq2  = (const float*)d_in[23];
    const float* bq2  = (const float*)d_in[24];

    float* ws = (float*)d_ws;
    float* h      = ws;                            // N*64
    float* agg    = h + (size_t)N * 64;            // N*64
    float* part_p = agg + (size_t)N * 64;          // PC*1024
    float* part_c = part_p + (size_t)PC * 1024;    // PC*16
    float* fend   = part_c + PC * 16;
    __hip_bfloat16* hb     = (__hip_bfloat16*)fend;          // N*96
    __hip_bfloat16* W2hi   = hb + (size_t)N * HS;            // 65536
    __hip_bfloat16* Wm1zhi = W2hi + 65536;                   // 143360
    __hip_bfloat16* Wu1hi  = Wm1zhi + 143360;                // 135168
    __hip_bfloat16* Wu1lo  = Wu1hi + 135168;
    __hip_bfloat16* Wu2hi  = Wu1lo + 135168;                 // 65536
    __hip_bfloat16* Wu2lo  = Wu2hi + 65536;
    __hip_bfloat16* Wp1hi  = Wu2lo + 65536;                  // 32768
    __hip_bfloat16* Wp1lo  = Wp1hi + 32768;
    __hip_bfloat16* Wp2hi  = Wp1lo + 32768;
    __hip_bfloat16* Wp2lo  = Wp2hi + 32768;

    k_reorder<<<1856, 256, 0, stream>>>(Wm2, Wm1, Wu1, Wu2, Wp1, Wp2,
                                        W2hi, Wm1zhi, Wu1hi, Wu1lo,
                                        Wu2hi, Wu2lo, Wp1hi, Wp1lo, Wp2hi, Wp2lo);

    k_embed_hb<<<625, 256, 0, stream>>>(x, anf, na, W_emb, b_emb, h, hb, agg);
    k_edge<<<E / 128, 256, 0, stream>>>(eidx, ea, amf, hb,
                                        Wm1zhi, bm1, W2hi, bm2, agg);
    k_upd_hb<<<625, 256, 0, stream>>>(h, anf, na, agg,
                                      Wu1hi, Wu1lo, bu1,
                                      Wu2hi, Wu2lo, bu2,
                                      h, hb, agg);
    k_edge<<<E / 128, 256, 0, stream>>>(eidx, ea, amf, hb,
                                        Wm1zhi + 71680, bm1 + 64,
                                        W2hi + 32768, bm2 + 64, agg);
    k_upd_prepool<<<625, 256, 0, stream>>>(h, anf, na, agg, batch,
                                           Wu1hi + 67584, Wu1lo + 67584, bu1 + 64,
                                           Wu2hi + 32768, Wu2lo + 32768, bu2 + 64,
                                           Wp1hi, Wp1lo, bp1, Wp2hi, Wp2lo, bp2,
                                           part_p, part_c);
    k_final<<<B, 256, 0, stream>>>(part_p, part_c, Wq1, bq1, Wq2, bq2, (float*)d_out);
}

// Round 19
// 383.676 us; speedup vs baseline: 1.1567x; 1.1567x over previous
//
#include <hip/hip_runtime.h>
#include <hip/hip_bf16.h>
#include <math.h>

// Problem constants
constexpr int N = 10000;
constexpr int E = 160000;
constexpr int B = 16;
constexpr int POOL_CHUNKS = 80;   // 80 * 125 = 10000
constexpr int MS = 72;            // m_s row stride (bf16)
constexpr int HS = 96;            // hb row stride: 4 q-sections x 24 (17 used + pad)

typedef short bf16x8 __attribute__((ext_vector_type(8)));
typedef short bf16x4 __attribute__((ext_vector_type(4)));
typedef float f32x4 __attribute__((ext_vector_type(4)));

__device__ __forceinline__ float silu_f(float x) {
    return x / (1.0f + __expf(-x));
}
__device__ __forceinline__ float bf2f(short s) {
    union { unsigned u; float f; } c; c.u = (unsigned)(unsigned short)s << 16; return c.f;
}

// ---------------- weight reorders (q-major i-mapping) ----------------
__global__ __launch_bounds__(256) void k_w2(
        const float* __restrict__ Wsrc,
        __hip_bfloat16* __restrict__ Whi, __hip_bfloat16* __restrict__ Wlo) {
    int idx = blockIdx.x * 256 + threadIdx.x;
    int l = idx >> 15;
    int rem = idx & 32767;
    int kk = rem >> 11;
    int nt = (rem >> 9) & 3;
    int c  = (rem >> 5) & 15;
    int q  = (rem >> 3) & 3;
    int j  = rem & 7;
    int i = q * 16 + kk;
    int k = nt * 16 + c;
    float wv = Wsrc[(size_t)l * 32768 + i * 512 + j * 64 + k];
    __hip_bfloat16 hi = __float2bfloat16(wv);
    Whi[idx] = hi;
    Wlo[idx] = __float2bfloat16(wv - __bfloat162float(hi));
}

// bf16 hi-only variant (edge phase 2)
__global__ __launch_bounds__(256) void k_w2h(
        const float* __restrict__ Wsrc, __hip_bfloat16* __restrict__ Whi) {
    int idx = blockIdx.x * 256 + threadIdx.x;
    int l = idx >> 15;
    int rem = idx & 32767;
    int kk = rem >> 11;
    int nt = (rem >> 9) & 3;
    int c  = (rem >> 5) & 15;
    int q  = (rem >> 3) & 3;
    int j  = rem & 7;
    int i = q * 16 + kk;
    int k = nt * 16 + c;
    Whi[idx] = __float2bfloat16(Wsrc[(size_t)l * 32768 + i * 512 + j * 64 + k]);
}

__global__ __launch_bounds__(256) void k_wu1(
        const float* __restrict__ Wu1,
        __hip_bfloat16* __restrict__ Whi, __hip_bfloat16* __restrict__ Wlo) {
    int idx = blockIdx.x * 256 + threadIdx.x;    // 2 * 67584
    int l = idx / 67584;
    int rem = idx % 67584;
    int kk = rem / 2048;          // 0..32
    int r2 = rem % 2048;
    int nt = (r2 >> 9) & 3;
    int c  = (r2 >> 5) & 15;
    int q  = (r2 >> 3) & 3;
    int j  = r2 & 7;
    int i = q * 33 + kk;          // 0..131
    float wv = (i < 129) ? Wu1[(size_t)l * 129 * 512 + i * 512 + j * 64 + nt * 16 + c] : 0.f;
    __hip_bfloat16 hi = __float2bfloat16(wv);
    Whi[idx] = hi;
    Wlo[idx] = __float2bfloat16(wv - __bfloat162float(hi));
}

__global__ __launch_bounds__(256) void k_wm1z(
        const float* __restrict__ Wm1, __hip_bfloat16* __restrict__ Whi) {
    int idx = blockIdx.x * 256 + threadIdx.x;   // 2 * 71680
    int l = idx / 71680;
    int rem = idx % 71680;
    int kkn = rem >> 9;          // 0..139
    int off = rem & 511;
    int kk = kkn >> 2;
    int nt = kkn & 3;
    int c16 = off >> 5;
    int q = (off >> 3) & 3;
    int j = off & 7;
    int k = nt * 16 + c16;
    int wi = -1;
    if (kk < 17) { int i = q * 17 + kk; if (i <= 64) wi = i; }
    else if (kk < 34) { int s = q * 17 + (kk - 17); if (s <= 64) wi = 65 + s; }
    else { if (q == 0) wi = 130; }
    float wv = (wi >= 0) ? Wm1[((size_t)l * 131 + wi) * 512 + j * 64 + k] : 0.f;
    Whi[idx] = __float2bfloat16(wv);
}

// ---------------- device helper: one z-GEMM stage (hi/lo), 4 waves split K, q-major x ----------------
__device__ __forceinline__ void zgemm_stage(
        const __hip_bfloat16* xsrc, int xstride, int kkmax, int Lq,
        int w, int c16, int q, int lofs, const float* naA,
        const __hip_bfloat16* __restrict__ Whi, const __hip_bfloat16* __restrict__ Wlo,
        float (*part_s)[16][64]) {
    f32x4 zero4 = {0.f, 0.f, 0.f, 0.f};
    f32x4 acc[4];
#pragma unroll
    for (int nt = 0; nt < 4; ++nt) acc[nt] = zero4;
    for (int kk = w; kk < kkmax; kk += 4) {
        bf16x8 bh[4], bl[4];
#pragma unroll
        for (int nt = 0; nt < 4; ++nt) {
            int off = (kk * 4 + nt) * 512 + lofs;
            bh[nt] = *(const bf16x8*)(Whi + off);
            bl[nt] = *(const bf16x8*)(Wlo + off);
        }
        float mv = __bfloat162float(xsrc[c16 * xstride + q * Lq + kk]);
        union { bf16x8 v; __hip_bfloat16 hx[8]; } au;
#pragma unroll
        for (int j = 0; j < 8; ++j) au.hx[j] = __float2bfloat16(mv * naA[j]);
#pragma unroll
        for (int nt = 0; nt < 4; ++nt) {
            acc[nt] = __builtin_amdgcn_mfma_f32_16x16x32_bf16(au.v, bh[nt], acc[nt], 0, 0, 0);
            acc[nt] = __builtin_amdgcn_mfma_f32_16x16x32_bf16(au.v, bl[nt], acc[nt], 0, 0, 0);
        }
    }
#pragma unroll
    for (int nt = 0; nt < 4; ++nt)
#pragma unroll
        for (int r = 0; r < 4; ++r) part_s[w][q * 4 + r][nt * 16 + c16] = acc[nt][r];
}

// ---------------- K1: embed -> h fp32 + hb (q-sectioned) + agg zero ----------------
__global__ __launch_bounds__(256) void k_embed_hb(
        const float* __restrict__ x, const float* __restrict__ anf,
        const float* __restrict__ na, const float* __restrict__ W_emb,
        const float* __restrict__ b_emb,
        float* __restrict__ h, __hip_bfloat16* __restrict__ hb, float* __restrict__ agg) {
    __shared__ float xs[16][18];
    __shared__ float na_s[16][8];
    int tid = threadIdx.x, w = tid >> 6, l = tid & 63;
    int n0 = blockIdx.x * 16;
    {
        int r = tid >> 4, c = tid & 15;
        xs[r][c] = x[(size_t)(n0 + r) * 16 + c];
    }
    if (tid < 16) xs[tid][16] = anf[n0 + tid];
    if (tid < 128) na_s[tid >> 3][tid & 7] = na[(size_t)n0 * 8 + tid];
    float4 z4 = {0.f, 0.f, 0.f, 0.f};
    ((float4*)(agg + (size_t)blockIdx.x * 1024))[tid] = z4;
    for (int t = tid; t < 192; t += 256)
        ((float4*)(hb + (size_t)n0 * HS))[t] = z4;
    __syncthreads();
    float acc[4];
#pragma unroll
    for (int t = 0; t < 4; ++t) acc[t] = b_emb[l];
    for (int i = 0; i < 17; ++i) {
#pragma unroll
        for (int j = 0; j < 8; ++j) {
            float wv = W_emb[(i * 8 + j) * 64 + l];
#pragma unroll
            for (int t = 0; t < 4; ++t) {
                int nn = w * 4 + t;
                acc[t] = fmaf(xs[nn][i] * na_s[nn][j], wv, acc[t]);
            }
        }
    }
    int slot = (l / 17) * 24 + l % 17;
#pragma unroll
    for (int t = 0; t < 4; ++t) {
        int n = n0 + w * 4 + t;
        h[(size_t)n * 64 + l] = acc[t];
        hb[(size_t)n * HS + slot] = __float2bfloat16(acc[t]);
    }
    if (tid < 16) hb[(size_t)(n0 + tid) * HS + 85] = __float2bfloat16(xs[tid][16]);  // i=64 -> 3*24+13
}

// ---------------- K3: edge kernel (R16-exact) ----------------
__global__ __launch_bounds__(256, 4) void k_edge(
        const int* __restrict__ eidx, const float* __restrict__ ea,
        const float* __restrict__ amf, const __hip_bfloat16* __restrict__ hb,
        const __hip_bfloat16* __restrict__ W1hi, const float* __restrict__ bm1_l,
        const __hip_bfloat16* __restrict__ W2hi,
        const float* __restrict__ bm2_l, float* __restrict__ agg) {
    __shared__ __align__(16) __hip_bfloat16 m_s[128 * MS];
    __shared__ float ea_s[128][9];
    __shared__ float amf_s[128];
    __shared__ int src_s[128], dst_s[128];
    __shared__ float bm1_s[64], bm2_s[64];
    int tid = threadIdx.x;
    int l = tid & 63, w = tid >> 6;
    int e0 = blockIdx.x * 128;
    for (int idx = tid; idx < 128; idx += 256) {
        src_s[idx] = eidx[e0 + idx];
        dst_s[idx] = eidx[E + e0 + idx];
        amf_s[idx] = amf[e0 + idx];
    }
    for (int idx = tid; idx < 1024; idx += 256) ea_s[idx >> 3][idx & 7] = ea[(size_t)e0 * 8 + idx];
    if (tid < 64) { bm1_s[tid] = bm1_l[tid]; bm2_s[tid] = bm2_l[tid]; }
    __syncthreads();

    int c16 = l & 15, q = l >> 4;
    int e0w = w * 32;
    float eaA[2][8];
    float amfA[2];
#pragma unroll
    for (int mt = 0; mt < 2; ++mt) {
#pragma unroll
        for (int j = 0; j < 8; ++j) eaA[mt][j] = ea_s[e0w + mt * 16 + c16][j];
        amfA[mt] = amf_s[e0w + mt * 16 + c16];
    }
    int lofs = (c16 * 4 + q) * 8;
    f32x4 zero4 = {0.f, 0.f, 0.f, 0.f};

    bf16x4 xD[2][5], xS[2][5];
#pragma unroll
    for (int mt = 0; mt < 2; ++mt) {
        const __hip_bfloat16* bd = hb + (size_t)dst_s[e0w + mt * 16 + c16] * HS + q * 24;
        const __hip_bfloat16* bs = hb + (size_t)src_s[e0w + mt * 16 + c16] * HS + q * 24;
#pragma unroll
        for (int t = 0; t < 5; ++t) {
            xD[mt][t] = *(const bf16x4*)(bd + t * 4);
            xS[mt][t] = *(const bf16x4*)(bs + t * 4);
        }
    }

    // phase 1
    f32x4 acc1[2][4];
#pragma unroll
    for (int mt = 0; mt < 2; ++mt)
#pragma unroll
        for (int nt = 0; nt < 4; ++nt) acc1[mt][nt] = zero4;
#pragma unroll
    for (int kk = 0; kk < 17; ++kk) {
        bf16x8 bh[4];
#pragma unroll
        for (int nt = 0; nt < 4; ++nt)
            bh[nt] = *(const bf16x8*)(W1hi + (kk * 4 + nt) * 512 + lofs);
#pragma unroll
        for (int mt = 0; mt < 2; ++mt) {
            float xv = bf2f(xD[mt][kk >> 2][kk & 3]);
            union { bf16x8 v; __hip_bfloat16 hx[8]; } au;
#pragma unroll
            for (int j = 0; j < 8; ++j) au.hx[j] = __float2bfloat16(xv * eaA[mt][j]);
#pragma unroll
            for (int nt = 0; nt < 4; ++nt)
                acc1[mt][nt] = __builtin_amdgcn_mfma_f32_16x16x32_bf16(au.v, bh[nt], acc1[mt][nt], 0, 0, 0);
        }
    }
#pragma unroll
    for (int kk = 0; kk < 17; ++kk) {
        bf16x8 bh[4];
#pragma unroll
        for (int nt = 0; nt < 4; ++nt)
            bh[nt] = *(const bf16x8*)(W1hi + ((17 + kk) * 4 + nt) * 512 + lofs);
#pragma unroll
        for (int mt = 0; mt < 2; ++mt) {
            float xv = bf2f(xS[mt][kk >> 2][kk & 3]);
            union { bf16x8 v; __hip_bfloat16 hx[8]; } au;
#pragma unroll
            for (int j = 0; j < 8; ++j) au.hx[j] = __float2bfloat16(xv * eaA[mt][j]);
#pragma unroll
            for (int nt = 0; nt < 4; ++nt)
                acc1[mt][nt] = __builtin_amdgcn_mfma_f32_16x16x32_bf16(au.v, bh[nt], acc1[mt][nt], 0, 0, 0);
        }
    }
    {   // amf chunk
        bf16x8 bh[4];
#pragma unroll
        for (int nt = 0; nt < 4; ++nt)
            bh[nt] = *(const bf16x8*)(W1hi + (34 * 4 + nt) * 512 + lofs);
#pragma unroll
        for (int mt = 0; mt < 2; ++mt) {
            float xv = (q == 0) ? amfA[mt] : 0.f;
            union { bf16x8 v; __hip_bfloat16 hx[8]; } au;
#pragma unroll
            for (int j = 0; j < 8; ++j) au.hx[j] = __float2bfloat16(xv * eaA[mt][j]);
#pragma unroll
            for (int nt = 0; nt < 4; ++nt)
                acc1[mt][nt] = __builtin_amdgcn_mfma_f32_16x16x32_bf16(au.v, bh[nt], acc1[mt][nt], 0, 0, 0);
        }
    }
#pragma unroll
    for (int mt = 0; mt < 2; ++mt)
#pragma unroll
        for (int nt = 0; nt < 4; ++nt) {
            int kd = nt * 16 + c16;
            float bias = bm1_s[kd];
#pragma unroll
            for (int r = 0; r < 4; ++r) {
                int e = e0w + mt * 16 + q * 4 + r;
                m_s[e * MS + kd] = __float2bfloat16(silu_f(bias + acc1[mt][nt][r]));
            }
        }

    // phase 2 (hi-only)
    bf16x4 mR[2][4];
#pragma unroll
    for (int mt = 0; mt < 2; ++mt)
#pragma unroll
        for (int t = 0; t < 4; ++t)
            mR[mt][t] = *(const bf16x4*)&m_s[(e0w + mt * 16 + c16) * MS + q * 16 + t * 4];

    f32x4 acc[2][4];
#pragma unroll
    for (int mt = 0; mt < 2; ++mt)
#pragma unroll
        for (int nt = 0; nt < 4; ++nt) acc[mt][nt] = zero4;
#pragma unroll
    for (int kk = 0; kk < 16; ++kk) {
        bf16x8 bh[4];
#pragma unroll
        for (int nt = 0; nt < 4; ++nt)
            bh[nt] = *(const bf16x8*)(W2hi + (kk * 4 + nt) * 512 + lofs);
#pragma unroll
        for (int mt = 0; mt < 2; ++mt) {
            float mv = bf2f(mR[mt][kk >> 2][kk & 3]);
            union { bf16x8 v; __hip_bfloat16 h[8]; } au;
#pragma unroll
            for (int j = 0; j < 8; ++j) au.h[j] = __float2bfloat16(mv * eaA[mt][j]);
#pragma unroll
            for (int nt = 0; nt < 4; ++nt)
                acc[mt][nt] = __builtin_amdgcn_mfma_f32_16x16x32_bf16(au.v, bh[nt], acc[mt][nt], 0, 0, 0);
        }
    }
#pragma unroll
    for (int mt = 0; mt < 2; ++mt)
#pragma unroll
        for (int nt = 0; nt < 4; ++nt) {
            int kd = nt * 16 + c16;
            float bias = bm2_s[kd];
#pragma unroll
            for (int r = 0; r < 4; ++r) {
                int e = e0w + mt * 16 + q * 4 + r;
                float v = silu_f(bias + acc[mt][nt][r]);
                atomicAdd(&agg[(size_t)dst_s[e] * 64 + kd], v);
            }
        }
}

// ---------------- K4: node update + write h/hb + agg zero ----------------
__global__ __launch_bounds__(256) void k_upd_hb(
        const float* __restrict__ h_in, const float* __restrict__ anf,
        const float* __restrict__ na, const float* __restrict__ agg_in,
        const __hip_bfloat16* __restrict__ W1hi, const __hip_bfloat16* __restrict__ W1lo,
        const float* __restrict__ bu1_l,
        const __hip_bfloat16* __restrict__ W2hi_, const __hip_bfloat16* __restrict__ W2lo_,
        const float* __restrict__ bu2_l,
        float* __restrict__ h, __hip_bfloat16* __restrict__ hb, float* __restrict__ agg) {
    __shared__ __align__(16) __hip_bfloat16 xa_s[16 * 136];
    __shared__ __align__(16) __hip_bfloat16 u1_s[16 * 72];
    __shared__ float part_s[4][16][64];
    int tid = threadIdx.x;
    int w = tid >> 6, l = tid & 63;
    int n0 = blockIdx.x * 16;
    for (int idx = tid; idx < 16 * 132; idx += 256) {
        int r = idx / 132, c = idx % 132;
        int n = n0 + r;
        float v;
        if (c < 64) v = h_in[(size_t)n * 64 + c];
        else if (c == 64) v = anf[n];
        else if (c < 129) v = agg_in[(size_t)n * 64 + (c - 65)];
        else v = 0.f;
        xa_s[r * 136 + c] = __float2bfloat16(v);
    }
    int c16 = l & 15, q = l >> 4;
    float naA[8];
#pragma unroll
    for (int j = 0; j < 8; ++j) naA[j] = na[(size_t)(n0 + c16) * 8 + j];
    __syncthreads();
    float4 z4 = {0.f, 0.f, 0.f, 0.f};
    ((float4*)(agg + (size_t)blockIdx.x * 1024))[tid] = z4;
    for (int t = tid; t < 192; t += 256)
        ((float4*)(hb + (size_t)n0 * HS))[t] = z4;
    int lofs = (c16 * 4 + q) * 8;
    zgemm_stage(xa_s, 136, 33, 33, w, c16, q, lofs, naA, W1hi, W1lo, part_s);
    __syncthreads();
    for (int t = tid; t < 1024; t += 256) {
        int row = t >> 6, col = t & 63;
        float v = part_s[0][row][col] + part_s[1][row][col] + part_s[2][row][col] +
                  part_s[3][row][col] + bu1_l[col];
        u1_s[row * 72 + col] = __float2bfloat16(silu_f(v));
    }
    __syncthreads();
    zgemm_stage(u1_s, 72, 16, 16, w, c16, q, lofs, naA, W2hi_, W2lo_, part_s);
    __syncthreads();
    for (int t = tid; t < 1024; t += 256) {
        int row = t >> 6, col = t & 63;
        float v = part_s[0][row][col] + part_s[1][row][col] + part_s[2][row][col] +
                  part_s[3][row][col] + bu2_l[col];
        int n = n0 + row;
        float hn = h[(size_t)n * 64 + col] + v;
        h[(size_t)n * 64 + col] = hn;
        hb[(size_t)n * HS + (col / 17) * 24 + col % 17] = __float2bfloat16(hn);
    }
    if (tid < 16) hb[(size_t)(n0 + tid) * HS + 85] = __float2bfloat16(anf[n0 + tid]);
}

// ---------------- K6: fused node update (layer 1) + prepool -> p2 ----------------
__global__ __launch_bounds__(256) void k_upd_prepool(
        const float* __restrict__ h_in, const float* __restrict__ anf,
        const float* __restrict__ na, const float* __restrict__ agg_in,
        const __hip_bfloat16* __restrict__ W1hi, const __hip_bfloat16* __restrict__ W1lo,
        const float* __restrict__ bu1_l,
        const __hip_bfloat16* __restrict__ W2hi_, const __hip_bfloat16* __restrict__ W2lo_,
        const float* __restrict__ bu2_l,
        const __hip_bfloat16* __restrict__ Wp1hi, const __hip_bfloat16* __restrict__ Wp1lo,
        const float* __restrict__ bp1,
        const __hip_bfloat16* __restrict__ Wp2hi, const __hip_bfloat16* __restrict__ Wp2lo,
        const float* __restrict__ bp2,
        float* __restrict__ p2) {
    __shared__ __align__(16) __hip_bfloat16 xa_s[16 * 136];
    __shared__ __align__(16) __hip_bfloat16 u1_s[16 * 72];
    __shared__ __align__(16) __hip_bfloat16 x2_s[16 * 72];
    __shared__ float part_s[4][16][64];
    int tid = threadIdx.x;
    int w = tid >> 6, l = tid & 63;
    int n0 = blockIdx.x * 16;
    for (int idx = tid; idx < 16 * 132; idx += 256) {
        int r = idx / 132, c = idx % 132;
        int n = n0 + r;
        float v;
        if (c < 64) v = h_in[(size_t)n * 64 + c];
        else if (c == 64) v = anf[n];
        else if (c < 129) v = agg_in[(size_t)n * 64 + (c - 65)];
        else v = 0.f;
        xa_s[r * 136 + c] = __float2bfloat16(v);
    }
    int c16 = l & 15, q = l >> 4;
    float naA[8];
#pragma unroll
    for (int j = 0; j < 8; ++j) naA[j] = na[(size_t)(n0 + c16) * 8 + j];
    __syncthreads();
    int lofs = (c16 * 4 + q) * 8;
    zgemm_stage(xa_s, 136, 33, 33, w, c16, q, lofs, naA, W1hi, W1lo, part_s);
    __syncthreads();
    for (int t = tid; t < 1024; t += 256) {
        int row = t >> 6, col = t & 63;
        float v = part_s[0][row][col] + part_s[1][row][col] + part_s[2][row][col] +
                  part_s[3][row][col] + bu1_l[col];
        u1_s[row * 72 + col] = __float2bfloat16(silu_f(v));
    }
    __syncthreads();
    zgemm_stage(u1_s, 72, 16, 16, w, c16, q, lofs, naA, W2hi_, W2lo_, part_s);
    __syncthreads();
    for (int t = tid; t < 1024; t += 256) {
        int row = t >> 6, col = t & 63;
        float v = part_s[0][row][col] + part_s[1][row][col] + part_s[2][row][col] +
                  part_s[3][row][col] + bu2_l[col];
        float hn = h_in[(size_t)(n0 + row) * 64 + col] + v;
        x2_s[row * 72 + col] = __float2bfloat16(hn);
    }
    __syncthreads();
    zgemm_stage(x2_s, 72, 16, 16, w, c16, q, lofs, naA, Wp1hi, Wp1lo, part_s);
    __syncthreads();
    for (int t = tid; t < 1024; t += 256) {
        int row = t >> 6, col = t & 63;
        float v = part_s[0][row][col] + part_s[1][row][col] + part_s[2][row][col] +
                  part_s[3][row][col] + bp1[col];
        u1_s[row * 72 + col] = __float2bfloat16(silu_f(v));
    }
    __syncthreads();
    zgemm_stage(u1_s, 72, 16, 16, w, c16, q, lofs, naA, Wp2hi, Wp2lo, part_s);
    __syncthreads();
    for (int t = tid; t < 1024; t += 256) {
        int row = t >> 6, col = t & 63;
        float v = part_s[0][row][col] + part_s[1][row][col] + part_s[2][row][col] +
                  part_s[3][row][col] + bp2[col];
        p2[(size_t)(n0 + row) * 64 + col] = v;
    }
}

// ---------------- K_pool ----------------
__global__ __launch_bounds__(256) void k_pool(
        const float* __restrict__ p2, const int* __restrict__ batch,
        float* __restrict__ partial_p, float* __restrict__ partial_cnt) {
    __shared__ float acc_s[16 * 64];
    __shared__ float cnt_s[16];
    int tid = threadIdx.x;
    for (int idx = tid; idx < 1024; idx += 256) acc_s[idx] = 0.f;
    if (tid < 16) cnt_s[tid] = 0.f;
    __syncthreads();
    int w = tid >> 6, k = tid & 63;
    int base = blockIdx.x * 125;
    for (int i = 0; i < 32; ++i) {
        int nl = i * 4 + w;
        if (nl < 125) {
            int n = base + nl;
            int b = batch[n];
            atomicAdd(&acc_s[b * 64 + k], p2[(size_t)n * 64 + k]);
            if (k == 0) atomicAdd(&cnt_s[b], 1.0f);
        }
    }
    __syncthreads();
    for (int idx = tid; idx < 1024; idx += 256)
        partial_p[(size_t)blockIdx.x * 1024 + idx] = acc_s[idx];
    if (tid < 16) partial_cnt[blockIdx.x * 16 + tid] = cnt_s[tid];
}

// ---------------- K7: reduce partials, mean, final MLP ----------------
__global__ __launch_bounds__(1024) void k_final(
        const float* __restrict__ partial_p, const float* __restrict__ partial_cnt,
        const float* __restrict__ Wq1, const float* __restrict__ bq1,
        const float* __restrict__ Wq2, const float* __restrict__ bq2,
        float* __restrict__ out) {
    __shared__ float g[16][64];
    int b = threadIdx.x >> 6, k = threadIdx.x & 63;
    float s = 0.f, cc = 0.f;
    for (int c = 0; c < POOL_CHUNKS; ++c) s += partial_p[(size_t)c * 1024 + b * 64 + k];
    for (int c = 0; c < POOL_CHUNKS; ++c) cc += partial_cnt[c * 16 + b];
    g[b][k] = s / fmaxf(cc, 1.0f);
    __syncthreads();
    float acc = bq1[k];
#pragma unroll
    for (int i = 0; i < 64; ++i) acc = fmaf(g[b][i], Wq1[i * 64 + k], acc);
    float v = silu_f(acc) * Wq2[k];
#pragma unroll
    for (int off = 32; off > 0; off >>= 1) v += __shfl_down(v, off, 64);
    if (k == 0) out[b] = v + bq2[0];
}

extern "C" void kernel_launch(void* const* d_in, const int* in_sizes, int n_in,
                              void* d_out, int out_size, void* d_ws, size_t ws_size,
                              hipStream_t stream) {
    const float* x    = (const float*)d_in[0];
    const int*   eidx = (const int*)  d_in[1];
    const float* ea   = (const float*)d_in[2];
    const float* na   = (const float*)d_in[3];
    const float* amf  = (const float*)d_in[4];
    const float* anf  = (const float*)d_in[5];
    const int*   batch= (const int*)  d_in[6];
    const float* W_emb= (const float*)d_in[7];
    const float* b_emb= (const float*)d_in[8];
    const float* Wm1  = (const float*)d_in[9];
    const float* bm1  = (const float*)d_in[10];
    const float* Wm2  = (const float*)d_in[11];
    const float* bm2  = (const float*)d_in[12];
    const float* Wu1  = (const float*)d_in[13];
    const float* bu1  = (const float*)d_in[14];
    const float* Wu2  = (const float*)d_in[15];
    const float* bu2  = (const float*)d_in[16];
    const float* Wp1  = (const float*)d_in[17];
    const float* bp1  = (const float*)d_in[18];
    const float* Wp2  = (const float*)d_in[19];
    const float* bp2  = (const float*)d_in[20];
    const float* Wq1  = (const float*)d_in[21];
    const float* bq1  = (const float*)d_in[22];
    const float* Wq2  = (const float*)d_in[23];
    const float* bq2  = (const float*)d_in[24];

    float* ws = (float*)d_ws;
    float* h      = ws;                            // N*64
    float* agg    = h + (size_t)N * 64;            // N*64
    float* p2     = agg + (size_t)N * 64;          // N*64
    float* part_p = p2 + (size_t)N * 64;           // 80*1024
    float* part_c = part_p + POOL_CHUNKS * 1024;   // 80*16
    float* fend   = part_c + POOL_CHUNKS * 16;
    __hip_bfloat16* hb     = (__hip_bfloat16*)fend;          // N*96
    __hip_bfloat16* W2hi   = hb + (size_t)N * HS;            // 2*32768
    __hip_bfloat16* Wm1zhi = W2hi + 65536;                   // 2*71680
    __hip_bfloat16* Wu1hi  = Wm1zhi + 143360;                // 2*67584
    __hip_bfloat16* Wu1lo  = Wu1hi + 135168;
    __hip_bfloat16* Wu2hi  = Wu1lo + 135168;                 // 2*32768
    __hip_bfloat16* Wu2lo  = Wu2hi + 65536;
    __hip_bfloat16* Wp1hi  = Wu2lo + 65536;                  // 32768
    __hip_bfloat16* Wp1lo  = Wp1hi + 32768;
    __hip_bfloat16* Wp2hi  = Wp1lo + 32768;
    __hip_bfloat16* Wp2lo  = Wp2hi + 32768;

    k_w2h<<<256, 256, 0, stream>>>(Wm2, W2hi);
    k_wm1z<<<560, 256, 0, stream>>>(Wm1, Wm1zhi);
    k_wu1<<<528, 256, 0, stream>>>(Wu1, Wu1hi, Wu1lo);
    k_w2<<<256, 256, 0, stream>>>(Wu2, Wu2hi, Wu2lo);
    k_w2<<<128, 256, 0, stream>>>(Wp1, Wp1hi, Wp1lo);
    k_w2<<<128, 256, 0, stream>>>(Wp2, Wp2hi, Wp2lo);

    k_embed_hb<<<625, 256, 0, stream>>>(x, anf, na, W_emb, b_emb, h, hb, agg);
    k_edge<<<E / 128, 256, 0, stream>>>(eidx, ea, amf, hb,
                                        Wm1zhi, bm1, W2hi, bm2, agg);
    k_upd_hb<<<625, 256, 0, stream>>>(h, anf, na, agg,
                                      Wu1hi, Wu1lo, bu1,
                                      Wu2hi, Wu2lo, bu2,
                                      h, hb, agg);
    k_edge<<<E / 128, 256, 0, stream>>>(eidx, ea, amf, hb,
                                        Wm1zhi + 71680, bm1 + 64,
                                        W2hi + 32768, bm2 + 64, agg);
    k_upd_prepool<<<625, 256, 0, stream>>>(h, anf, na, agg,
                                           Wu1hi + 67584, Wu1lo + 67584, bu1 + 64,
                                           Wu2hi + 32768, Wu2lo + 32768, bu2 + 64,
                                           Wp1hi, Wp1lo, bp1, Wp2hi, Wp2lo, bp2, p2);
    k_pool<<<POOL_CHUNKS, 256, 0, stream>>>(p2, batch, part_p, part_c);
    k_final<<<1, 1024, 0, stream>>>(part_p, part_c, Wq1, bq1, Wq2, bq2, (float*)d_out);
}